// Round 7
// baseline (407.284 us; speedup 1.0000x reference)
//
#include <hip/hip_runtime.h>

typedef __attribute__((ext_vector_type(4))) float f32x4;
typedef __attribute__((ext_vector_type(8))) short short8;
typedef unsigned short ushort_t;
typedef unsigned int uint_t;

#define R_  32768
#define E_  192
#define V_  96
#define L_  6
#define EPS_ 1e-5f

#define NCHUNK 24
#define NT 144              // L_ * NCHUNK chunks
#define NP 72               // chunk pairs
#define CH_US 12288         // ushorts per chunk: 12 w1 frags + 12 w2 frags, 512 us each
#define CH_BYTES 24576
#define W2_OFF 12288        // byte offset of w2 fragment region within a chunk

__device__ __forceinline__ ushort_t f2bf(float f) {
    uint_t i = __builtin_bit_cast(uint_t, f);
    uint_t r = (i + 0x7fffu + ((i >> 16) & 1u)) >> 16;   // RNE
    return (ushort_t)r;
}
// packed f32 pair -> bf16x2 dword (RNE), single HW instr
__device__ __forceinline__ uint_t cvtpk(float a, float b) {
    uint_t r;
    asm("v_cvt_pk_bf16_f32 %0, %1, %2" : "=v"(r) : "v"(a), "v"(b));
    return r;
}

// async global->LDS DMA, 16B per lane
typedef __attribute__((address_space(1))) const uint_t as1_uint;
typedef __attribute__((address_space(3))) uint_t as3_uint;
__device__ __forceinline__ void glds16(const void* g, void* l) {
    __builtin_amdgcn_global_load_lds((as1_uint*)g, (as3_uint*)l, 16, 0, 0);
}
// 4 waves cover one 12 KiB w1 region: each wave stages 3 KiB
__device__ __forceinline__ void stage3(const char* gchunk, char* lbuf, int w, int lane) {
    const char* g = gchunk + w * 3072 + lane * 16;
    char* l = lbuf + w * 3072;
#pragma unroll
    for (int i = 0; i < 3; ++i) glds16(g + i * 1024, l + i * 1024);
}
// w2 fragments for chunk t: 12 x 1KiB, global (L1/L2-hot), register-resident
__device__ __forceinline__ void loadw2(uint4 (&d)[12], const ushort_t* wch, int t, int lane) {
    const char* p = (const char*)wch + (size_t)t * CH_BYTES + W2_OFF + lane * 16;
#pragma unroll
    for (int e = 0; e < 12; ++e) d[e] = *(const uint4*)(p + e * 1024);
}

// ---- LayerNorm on D-layout register state ----
__device__ __forceinline__ void lnD(f32x4 (&a)[12], const float* gp, const float* bp, int g) {
    float s = 0.f, sq = 0.f;
#pragma unroll
    for (int et = 0; et < 12; ++et)
#pragma unroll
        for (int r = 0; r < 4; ++r) { float x = a[et][r]; s += x; sq += x * x; }
    s += __shfl_xor(s, 16); sq += __shfl_xor(sq, 16);
    s += __shfl_xor(s, 32); sq += __shfl_xor(sq, 32);
    float mu = s * (1.f / 192.f);
    float ri = rsqrtf(sq * (1.f / 192.f) - mu * mu + EPS_);
#pragma unroll
    for (int et = 0; et < 12; ++et) {
        float4 gg = *(const float4*)(gp + et * 16 + g * 4);
        float4 bb = *(const float4*)(bp + et * 16 + g * 4);
        a[et][0] = (a[et][0] - mu) * ri * gg.x + bb.x;
        a[et][1] = (a[et][1] - mu) * ri * gg.y + bb.y;
        a[et][2] = (a[et][2] - mu) * ri * gg.z + bb.z;
        a[et][3] = (a[et][3] - mu) * ri * gg.w + bb.w;
    }
}

// ---- pack D-layout f32 state to bf16 and exchange into B-fragments ----
__device__ __forceinline__ void packex(const f32x4 (&a)[12], int lane, short8 (&xf)[6]) {
    uint_t pk[12][2];
#pragma unroll
    for (int et = 0; et < 12; ++et) {
        pk[et][0] = cvtpk(a[et][0], a[et][1]);
        pk[et][1] = cvtpk(a[et][2], a[et][3]);
    }
    const bool hi = (lane & 32) != 0;
    const int base = ((lane & 16) << 1) + (lane & 15);
#pragma unroll
    for (int kc = 0; kc < 6; ++kc) {
        uint_t dw[4];
#pragma unroll
        for (int d = 0; d < 4; ++d) {
            int src = base + (d >> 1) * 16;
            uint_t A = (uint_t)__shfl((int)pk[2 * kc][d & 1], src);
            uint_t B = (uint_t)__shfl((int)pk[2 * kc + 1][d & 1], src);
            dw[d] = hi ? B : A;
        }
        uint4 q; q.x = dw[0]; q.y = dw[1]; q.z = dw[2]; q.w = dw[3];
        xf[kc] = __builtin_bit_cast(short8, q);
    }
}

// ---- bias1+relu in D-layout, pack, exchange packed dwords -> h B-fragment ----
__device__ __forceinline__ short8 mk_hb(const f32x4& ah0, const f32x4& ah1,
                                        float4 b1a, float4 b1b, bool hi, int xbase) {
    float y00 = fmaxf(ah0[0] + b1a.x, 0.f), y01 = fmaxf(ah0[1] + b1a.y, 0.f);
    float y02 = fmaxf(ah0[2] + b1a.z, 0.f), y03 = fmaxf(ah0[3] + b1a.w, 0.f);
    float y10 = fmaxf(ah1[0] + b1b.x, 0.f), y11 = fmaxf(ah1[1] + b1b.y, 0.f);
    float y12 = fmaxf(ah1[2] + b1b.z, 0.f), y13 = fmaxf(ah1[3] + b1b.w, 0.f);
    uint_t pA0 = cvtpk(y00, y01), pA1 = cvtpk(y02, y03);
    uint_t pB0 = cvtpk(y10, y11), pB1 = cvtpk(y12, y13);
    uint_t dw[4];
#pragma unroll
    for (int d = 0; d < 4; ++d) {
        int src = xbase + (d >> 1) * 16;
        uint_t A = (uint_t)__shfl((int)((d & 1) ? pA1 : pA0), src);
        uint_t B = (uint_t)__shfl((int)((d & 1) ? pB1 : pB0), src);
        dw[d] = hi ? B : A;
    }
    uint4 hq; hq.x = dw[0]; hq.y = dw[1]; hq.z = dw[2]; hq.w = dw[3];
    return __builtin_bit_cast(short8, hq);
}

// ---------------- weight convert: fragment-ordered chunks ----------------
__global__ void wconv_k(const float* __restrict__ W1, const float* __restrict__ W2,
                        const float* __restrict__ Wf,
                        ushort_t* __restrict__ wch, ushort_t* __restrict__ wfr)
{
    int i = blockIdx.x * 256 + threadIdx.x;
    const int NW = 884736;
    if (i < NW) {   // w1 fragments: chunk t, block (kc*2+fi), lane li, elem j
        int t = i / 6144, wc = i % 6144;
        int blk = wc >> 9, li = (wc >> 3) & 63, j = wc & 7;
        int kc = blk >> 1, fi = blk & 1, g = li >> 4, c = li & 15;
        int cc = t % 24, lyr = t / 24;
        int e = kc * 32 + g * 8 + j, f = cc * 32 + fi * 16 + c;
        wch[(size_t)t * CH_US + wc] = f2bf(W1[((size_t)lyr * 192 + e) * 768 + f]);
        return;
    }
    i -= NW;
    if (i < NW) {   // w2 fragments: block et, lane li, elem j
        int t = i / 6144, wc = i % 6144;
        int et = wc >> 9, li = (wc >> 3) & 63, j = wc & 7;
        int g = li >> 4, c = li & 15;
        int cc = t % 24, lyr = t / 24;
        wch[(size_t)t * CH_US + 6144 + wc] =
            f2bf(W2[((size_t)lyr * 768 + cc * 32 + g * 8 + j) * 192 + et * 16 + c]);
        return;
    }
    i -= NW;
    if (i < 36 * 512) {   // head fragments: block (kc*6+vt)
        int blk = i >> 9, li = (i >> 3) & 63, j = i & 7;
        int kc = blk / 6, vt = blk % 6, g = li >> 4, c = li & 15;
        wfr[i] = f2bf(Wf[((size_t)kc * 32 + g * 8 + j) * 96 + vt * 16 + c]);
    }
}

// ---------------- the whole network, one kernel, 64 rows/block ----------------
// pair-bodies: 2 FFN chunks per barrier; w1 via LDS pair-dbuf, w2 register-resident
__global__ __launch_bounds__(256, 2) void net_k(
    const int* __restrict__ idxp, const int* __restrict__ tgp,
    const float* __restrict__ tok, const float* __restrict__ pos,
    const float* __restrict__ ln1g, const float* __restrict__ ln1b,
    const float* __restrict__ ln2g, const float* __restrict__ ln2b,
    const float* __restrict__ b1g, const float* __restrict__ b2g,
    const float* __restrict__ fng, const float* __restrict__ fnb,
    const float* __restrict__ bfb,
    const ushort_t* __restrict__ wch, const ushort_t* __restrict__ wfr,
    float* __restrict__ pred, float* __restrict__ partial)
{
    __shared__ __align__(16) ushort_t wlds[2][2 * 6144];    // 2 pair-buffers x 24 KiB
    __shared__ float lsred[4];

    const int tid = threadIdx.x, lane = tid & 63, w = tid >> 6;
    const int c = lane & 15, g = lane >> 4;
    const int myrow = blockIdx.x * 64 + w * 16 + c;

    // prologue: stage pair 0 w1, prefetch both chunks' w2 into registers
    stage3((const char*)wch,            (char*)&wlds[0][0],    w, lane);
    stage3((const char*)wch + CH_BYTES, (char*)&wlds[0][6144], w, lane);
    uint4 w2r0[12], w2r1[12];
    loadw2(w2r0, wch, 0, lane);
    loadw2(w2r1, wch, 1, lane);

    // embedding in D-layout: lane(g,c) holds x[e=et*16+g*4+r][row c]
    f32x4 axT[12];
    {
        int id = idxp[myrow];
        int tt = myrow & 127;
#pragma unroll
        for (int et = 0; et < 12; ++et) {
            float4 a = *(const float4*)(tok + (size_t)id * 192 + et * 16 + g * 4);
            float4 b = *(const float4*)(pos + (size_t)tt * 192 + et * 16 + g * 4);
            axT[et][0] = a.x + b.x; axT[et][1] = a.y + b.y;
            axT[et][2] = a.z + b.z; axT[et][3] = a.w + b.w;
        }
    }
    __syncthreads();

    const bool hi = (lane & 32) != 0;
    const int xbase = ((lane & 16) << 1) + (lane & 15);

    int q = 0;
#pragma unroll 1
    for (int l = 0; l < L_; ++l) {
        // n2 = LN2(LN1(x)) on D-layout state (params from global/L1)
        lnD(axT, ln1g + l * 192, ln1b + l * 192, g);
        lnD(axT, ln2g + l * 192, ln2b + l * 192, g);
        short8 xf[6];
        packex(axT, lane, xf);
#pragma unroll
        for (int et = 0; et < 12; ++et)
            { axT[et][0] = 0.f; axT[et][1] = 0.f; axT[et][2] = 0.f; axT[et][3] = 0.f; }

#pragma unroll 1
        for (int pp = 0; pp < 12; ++pp) {
            const int P = l * 12 + pp;            // global pair index
            const int cc0 = pp * 2, cc1 = cc0 + 1;

            // stage next pair's w1 into the other pair-buffer (latency under this body)
            if (P + 1 < NP) {
                const char* gnext = (const char*)wch + (size_t)(P + 1) * 2 * CH_BYTES;
                stage3(gnext,            (char*)&wlds[q ^ 1][0],    w, lane);
                stage3(gnext + CH_BYTES, (char*)&wlds[q ^ 1][6144], w, lane);
            }
            // bias1 for both chunks, issued early (L1-hot)
            const float* bl = b1g + l * 768;
            float4 b1a0 = *(const float4*)(bl + cc0 * 32 + g * 4);
            float4 b1b0 = *(const float4*)(bl + cc0 * 32 + 16 + g * 4);
            float4 b1a1 = *(const float4*)(bl + cc1 * 32 + g * 4);
            float4 b1b1 = *(const float4*)(bl + cc1 * 32 + 16 + g * 4);

            const char* wb = (const char*)&wlds[q][0] + lane * 16;

            // gemm1 chunk0
            uint4 wa[12];
#pragma unroll
            for (int k = 0; k < 12; ++k) wa[k] = *(const uint4*)(wb + k * 1024);
            f32x4 ah00 = {}, ah01 = {};
            __builtin_amdgcn_s_setprio(1);
#pragma unroll
            for (int kc = 0; kc < 6; ++kc) {
                ah00 = __builtin_amdgcn_mfma_f32_16x16x32_bf16(__builtin_bit_cast(short8, wa[kc * 2]),     xf[kc], ah00, 0, 0, 0);
                ah01 = __builtin_amdgcn_mfma_f32_16x16x32_bf16(__builtin_bit_cast(short8, wa[kc * 2 + 1]), xf[kc], ah01, 0, 0, 0);
            }
            __builtin_amdgcn_s_setprio(0);

            // gemm1 chunk1 (wa reused; WAR resolves at issue, ds_reads overlap gemm1_0 exec)
            uint4 wa1[12];
#pragma unroll
            for (int k = 0; k < 12; ++k) wa1[k] = *(const uint4*)(wb + 12288 + k * 1024);
            f32x4 ah10 = {}, ah11 = {};
            __builtin_amdgcn_s_setprio(1);
#pragma unroll
            for (int kc = 0; kc < 6; ++kc) {
                ah10 = __builtin_amdgcn_mfma_f32_16x16x32_bf16(__builtin_bit_cast(short8, wa1[kc * 2]),     xf[kc], ah10, 0, 0, 0);
                ah11 = __builtin_amdgcn_mfma_f32_16x16x32_bf16(__builtin_bit_cast(short8, wa1[kc * 2 + 1]), xf[kc], ah11, 0, 0, 0);
            }
            __builtin_amdgcn_s_setprio(0);

            // exchange 0 (runs while gemm1_1 MFMAs execute), gemm2 chunk0
            short8 hb0 = mk_hb(ah00, ah01, b1a0, b1b0, hi, xbase);
            __builtin_amdgcn_s_setprio(1);
#pragma unroll
            for (int et = 0; et < 12; ++et)
                axT[et] = __builtin_amdgcn_mfma_f32_16x16x32_bf16(__builtin_bit_cast(short8, w2r0[et]), hb0, axT[et], 0, 0, 0);
            __builtin_amdgcn_s_setprio(0);
            // w2r0 consumed -> refill with next pair's chunk0 (completes by barrier drain)
            if (P + 1 < NP) loadw2(w2r0, wch, (P + 1) * 2, lane);

            // exchange 1, gemm2 chunk1
            short8 hb1 = mk_hb(ah10, ah11, b1a1, b1b1, hi, xbase);
            __builtin_amdgcn_s_setprio(1);
#pragma unroll
            for (int et = 0; et < 12; ++et)
                axT[et] = __builtin_amdgcn_mfma_f32_16x16x32_bf16(__builtin_bit_cast(short8, w2r1[et]), hb1, axT[et], 0, 0, 0);
            __builtin_amdgcn_s_setprio(0);
            if (P + 1 < NP) loadw2(w2r1, wch, (P + 1) * 2 + 1, lane);

            __syncthreads();     // one barrier per pair: drains glds + w2 refills
            q ^= 1;
        }

        // + bias2 (from global, L1-hot)
#pragma unroll
        for (int et = 0; et < 12; ++et) {
            float4 bb = *(const float4*)(b2g + l * 192 + et * 16 + g * 4);
            axT[et][0] += bb.x; axT[et][1] += bb.y; axT[et][2] += bb.z; axT[et][3] += bb.w;
        }
    }

    // ---- final LN + head ----
    lnD(axT, fng, fnb, g);
    short8 xf[6];
    packex(axT, lane, xf);
    f32x4 av[6] = {};
    __builtin_amdgcn_s_setprio(1);
#pragma unroll
    for (int kc = 0; kc < 6; ++kc)
#pragma unroll
        for (int vt = 0; vt < 6; ++vt) {
            short8 wf = *(const short8*)(wfr + (size_t)(kc * 6 + vt) * 512 + lane * 8);
            av[vt] = __builtin_amdgcn_mfma_f32_16x16x32_bf16(wf, xf[kc], av[vt], 0, 0, 0);
        }
    __builtin_amdgcn_s_setprio(0);

    float vv[6][4];
#pragma unroll
    for (int vt = 0; vt < 6; ++vt) {
        float4 bb = *(const float4*)(bfb + vt * 16 + g * 4);
        vv[vt][0] = av[vt][0] + bb.x;
        vv[vt][1] = av[vt][1] + bb.y;
        vv[vt][2] = av[vt][2] + bb.z;
        vv[vt][3] = av[vt][3] + bb.w;
    }
    float mx = -1e30f;
#pragma unroll
    for (int vt = 0; vt < 6; ++vt)
#pragma unroll
        for (int r = 0; r < 4; ++r) mx = fmaxf(mx, vv[vt][r]);
    mx = fmaxf(mx, __shfl_xor(mx, 16));
    mx = fmaxf(mx, __shfl_xor(mx, 32));
    float se = 0.f;
#pragma unroll
    for (int vt = 0; vt < 6; ++vt)
#pragma unroll
        for (int r = 0; r < 4; ++r) se += expf(vv[vt][r] - mx);
    se += __shfl_xor(se, 16);
    se += __shfl_xor(se, 32);
    float lse = logf(se) + mx;
    int tgt = tgp[myrow];
    float lsum = 0.f;
#pragma unroll
    for (int vt = 0; vt < 6; ++vt)
#pragma unroll
        for (int r = 0; r < 4; ++r)
            if (tgt == vt * 16 + g * 4 + r) lsum += lse - vv[vt][r];
#pragma unroll
    for (int vt = 0; vt < 6; ++vt) {
        float4 o;
        o.x = vv[vt][0]; o.y = vv[vt][1]; o.z = vv[vt][2]; o.w = vv[vt][3];
        *(float4*)(pred + (size_t)myrow * 96 + vt * 16 + g * 4) = o;
    }
#pragma unroll
    for (int m = 1; m < 64; m <<= 1) lsum += __shfl_xor(lsum, m);
    if (lane == 0) lsred[w] = lsum;
    __syncthreads();
    if (tid == 0) partial[blockIdx.x] = lsred[0] + lsred[1] + lsred[2] + lsred[3];
}

__global__ void lossred_k(const float* __restrict__ partial, float* __restrict__ out)
{
    __shared__ double sd[256];
    int t = threadIdx.x;
    sd[t] = (double)partial[t] + (double)partial[t + 256];
    __syncthreads();
    for (int s = 128; s > 0; s >>= 1) {
        if (t < s) sd[t] += sd[t + s];
        __syncthreads();
    }
    if (t == 0) out[0] = (float)(sd[0] / (double)R_);
}

extern "C" void kernel_launch(void* const* d_in, const int* in_sizes, int n_in,
                              void* d_out, int out_size, void* d_ws, size_t ws_size,
                              hipStream_t stream)
{
    (void)in_sizes; (void)n_in; (void)out_size; (void)ws_size;
    const int*   index   = (const int*)  d_in[0];
    const int*   targets = (const int*)  d_in[1];
    const float* tok     = (const float*)d_in[2];
    const float* pos     = (const float*)d_in[3];
    const float* ln1g    = (const float*)d_in[4];
    const float* ln1b    = (const float*)d_in[5];
    const float* ln2g    = (const float*)d_in[6];
    const float* ln2b    = (const float*)d_in[7];
    // d_in[8..10] = Wq/Wk/Wv: dead in the reference forward
    const float* W1      = (const float*)d_in[11];
    const float* b1      = (const float*)d_in[12];
    const float* W2      = (const float*)d_in[13];
    const float* b2      = (const float*)d_in[14];
    const float* fng     = (const float*)d_in[15];
    const float* fnb     = (const float*)d_in[16];
    const float* Wf      = (const float*)d_in[17];
    const float* bfv     = (const float*)d_in[18];

    ushort_t* wch = (ushort_t*)d_ws;                        // [144][12288] us (24576B chunks)
    ushort_t* wfr = wch + (size_t)NT * CH_US;               // [36][512] head fragments
    float* partial = (float*)(wfr + 36 * 512);              // [512]
    float* pred  = (float*)d_out;
    float* lossp = pred + (size_t)R_ * V_;

    const int nconv = 2 * 884736 + 36 * 512;                // 1787904 = 6984*256
    wconv_k<<<nconv / 256, 256, 0, stream>>>(W1, W2, Wf, wch, wfr);
    net_k<<<512, 256, 0, stream>>>(index, targets, tok, pos, ln1g, ln1b, ln2g, ln2b,
                                   b1, b2, fng, fnb, bfv, wch, wfr, pred, partial);
    lossred_k<<<1, 256, 0, stream>>>(partial, lossp);
}

// Round 8
// 224.236 us; speedup vs baseline: 1.8163x; 1.8163x over previous
//
#include <hip/hip_runtime.h>

typedef __attribute__((ext_vector_type(4))) float f32x4;
typedef __attribute__((ext_vector_type(8))) short short8;
typedef unsigned short ushort_t;
typedef unsigned int uint_t;

#define R_  32768
#define E_  192
#define V_  96
#define L_  6
#define EPS_ 1e-5f

#define NCHUNK 24
#define NT 144              // L_ * NCHUNK chunks
#define NP 72               // chunk pairs
#define CH_US 12288         // ushorts per chunk: 12 w1 frags + 12 w2 frags, 512 us each
#define CH_BYTES 24576
#define W2_OFF 12288        // byte offset of w2 fragment region within a chunk

__device__ __forceinline__ ushort_t f2bf(float f) {
    uint_t i = __builtin_bit_cast(uint_t, f);
    uint_t r = (i + 0x7fffu + ((i >> 16) & 1u)) >> 16;   // RNE
    return (ushort_t)r;
}
// packed f32 pair -> bf16x2 dword (RNE), single HW instr
__device__ __forceinline__ uint_t cvtpk(float a, float b) {
    uint_t r;
    asm("v_cvt_pk_bf16_f32 %0, %1, %2" : "=v"(r) : "v"(a), "v"(b));
    return r;
}

// async global->LDS DMA, 16B per lane
typedef __attribute__((address_space(1))) const uint_t as1_uint;
typedef __attribute__((address_space(3))) uint_t as3_uint;
__device__ __forceinline__ void glds16(const void* g, void* l) {
    __builtin_amdgcn_global_load_lds((as1_uint*)g, (as3_uint*)l, 16, 0, 0);
}
// 4 waves cover one 12 KiB w1 region: each wave stages 3 KiB
__device__ __forceinline__ void stage3(const char* gchunk, char* lbuf, int w, int lane) {
    const char* g = gchunk + w * 3072 + lane * 16;
    char* l = lbuf + w * 3072;
#pragma unroll
    for (int i = 0; i < 3; ++i) glds16(g + i * 1024, l + i * 1024);
}

// ---- LayerNorm on D-layout register state ----
__device__ __forceinline__ void lnD(f32x4 (&a)[12], const float* gp, const float* bp, int g) {
    float s = 0.f, sq = 0.f;
#pragma unroll
    for (int et = 0; et < 12; ++et)
#pragma unroll
        for (int r = 0; r < 4; ++r) { float x = a[et][r]; s += x; sq += x * x; }
    s += __shfl_xor(s, 16); sq += __shfl_xor(sq, 16);
    s += __shfl_xor(s, 32); sq += __shfl_xor(sq, 32);
    float mu = s * (1.f / 192.f);
    float ri = rsqrtf(sq * (1.f / 192.f) - mu * mu + EPS_);
#pragma unroll
    for (int et = 0; et < 12; ++et) {
        float4 gg = *(const float4*)(gp + et * 16 + g * 4);
        float4 bb = *(const float4*)(bp + et * 16 + g * 4);
        a[et][0] = (a[et][0] - mu) * ri * gg.x + bb.x;
        a[et][1] = (a[et][1] - mu) * ri * gg.y + bb.y;
        a[et][2] = (a[et][2] - mu) * ri * gg.z + bb.z;
        a[et][3] = (a[et][3] - mu) * ri * gg.w + bb.w;
    }
}

// ---- pack D-layout f32 state to bf16 and exchange into B-fragments ----
__device__ __forceinline__ void packex(const f32x4 (&a)[12], int lane, short8 (&xf)[6]) {
    uint_t pk[12][2];
#pragma unroll
    for (int et = 0; et < 12; ++et) {
        pk[et][0] = cvtpk(a[et][0], a[et][1]);
        pk[et][1] = cvtpk(a[et][2], a[et][3]);
    }
    const bool hi = (lane & 32) != 0;
    const int base = ((lane & 16) << 1) + (lane & 15);
#pragma unroll
    for (int kc = 0; kc < 6; ++kc) {
        uint_t dw[4];
#pragma unroll
        for (int d = 0; d < 4; ++d) {
            int src = base + (d >> 1) * 16;
            uint_t A = (uint_t)__shfl((int)pk[2 * kc][d & 1], src);
            uint_t B = (uint_t)__shfl((int)pk[2 * kc + 1][d & 1], src);
            dw[d] = hi ? B : A;
        }
        uint4 q; q.x = dw[0]; q.y = dw[1]; q.z = dw[2]; q.w = dw[3];
        xf[kc] = __builtin_bit_cast(short8, q);
    }
}

// ---- bias1+relu in D-layout, pack, exchange packed dwords -> h B-fragment ----
__device__ __forceinline__ short8 mk_hb(const f32x4& ah0, const f32x4& ah1,
                                        float4 b1a, float4 b1b, bool hi, int xbase) {
    float y00 = fmaxf(ah0[0] + b1a.x, 0.f), y01 = fmaxf(ah0[1] + b1a.y, 0.f);
    float y02 = fmaxf(ah0[2] + b1a.z, 0.f), y03 = fmaxf(ah0[3] + b1a.w, 0.f);
    float y10 = fmaxf(ah1[0] + b1b.x, 0.f), y11 = fmaxf(ah1[1] + b1b.y, 0.f);
    float y12 = fmaxf(ah1[2] + b1b.z, 0.f), y13 = fmaxf(ah1[3] + b1b.w, 0.f);
    uint_t pA0 = cvtpk(y00, y01), pA1 = cvtpk(y02, y03);
    uint_t pB0 = cvtpk(y10, y11), pB1 = cvtpk(y12, y13);
    uint_t dw[4];
#pragma unroll
    for (int d = 0; d < 4; ++d) {
        int src = xbase + (d >> 1) * 16;
        uint_t A = (uint_t)__shfl((int)((d & 1) ? pA1 : pA0), src);
        uint_t B = (uint_t)__shfl((int)((d & 1) ? pB1 : pB0), src);
        dw[d] = hi ? B : A;
    }
    uint4 hq; hq.x = dw[0]; hq.y = dw[1]; hq.z = dw[2]; hq.w = dw[3];
    return __builtin_bit_cast(short8, hq);
}

// ---------------- weight convert: fragment-ordered chunks ----------------
__global__ void wconv_k(const float* __restrict__ W1, const float* __restrict__ W2,
                        const float* __restrict__ Wf,
                        ushort_t* __restrict__ wch, ushort_t* __restrict__ wfr)
{
    int i = blockIdx.x * 256 + threadIdx.x;
    const int NW = 884736;
    if (i < NW) {   // w1 fragments: chunk t, block (kc*2+fi), lane li, elem j
        int t = i / 6144, wc = i % 6144;
        int blk = wc >> 9, li = (wc >> 3) & 63, j = wc & 7;
        int kc = blk >> 1, fi = blk & 1, g = li >> 4, c = li & 15;
        int cc = t % 24, lyr = t / 24;
        int e = kc * 32 + g * 8 + j, f = cc * 32 + fi * 16 + c;
        wch[(size_t)t * CH_US + wc] = f2bf(W1[((size_t)lyr * 192 + e) * 768 + f]);
        return;
    }
    i -= NW;
    if (i < NW) {   // w2 fragments: block et, lane li, elem j
        int t = i / 6144, wc = i % 6144;
        int et = wc >> 9, li = (wc >> 3) & 63, j = wc & 7;
        int g = li >> 4, c = li & 15;
        int cc = t % 24, lyr = t / 24;
        wch[(size_t)t * CH_US + 6144 + wc] =
            f2bf(W2[((size_t)lyr * 768 + cc * 32 + g * 8 + j) * 192 + et * 16 + c]);
        return;
    }
    i -= NW;
    if (i < 36 * 512) {   // head fragments: block (kc*6+vt)
        int blk = i >> 9, li = (i >> 3) & 63, j = i & 7;
        int kc = blk / 6, vt = blk % 6, g = li >> 4, c = li & 15;
        wfr[i] = f2bf(Wf[((size_t)kc * 32 + g * 8 + j) * 96 + vt * 16 + c]);
    }
}

// ---------------- the whole network, one kernel, 64 rows/block ----------------
// pair-bodies: 2 FFN chunks per barrier; w1 LDS pair-dbuf, ONE w2 register set
__global__ __launch_bounds__(256, 2) void net_k(
    const int* __restrict__ idxp, const int* __restrict__ tgp,
    const float* __restrict__ tok, const float* __restrict__ pos,
    const float* __restrict__ ln1g, const float* __restrict__ ln1b,
    const float* __restrict__ ln2g, const float* __restrict__ ln2b,
    const float* __restrict__ b1g, const float* __restrict__ b2g,
    const float* __restrict__ fng, const float* __restrict__ fnb,
    const float* __restrict__ bfb,
    const ushort_t* __restrict__ wch, const ushort_t* __restrict__ wfr,
    float* __restrict__ pred, float* __restrict__ partial)
{
    __shared__ __align__(16) ushort_t wlds[2][2 * 6144];    // 2 pair-buffers x 24 KiB
    __shared__ float lsred[4];

    const int tid = threadIdx.x, lane = tid & 63, w = tid >> 6;
    const int c = lane & 15, g = lane >> 4;
    const int myrow = blockIdx.x * 64 + w * 16 + c;

    // prologue: stage pair-0 w1 (both chunks)
    stage3((const char*)wch,            (char*)&wlds[0][0],    w, lane);
    stage3((const char*)wch + CH_BYTES, (char*)&wlds[0][6144], w, lane);

    // embedding in D-layout: lane(g,c) holds x[e=et*16+g*4+r][row c]
    f32x4 axT[12];
    {
        int id = idxp[myrow];
        int tt = myrow & 127;
#pragma unroll
        for (int et = 0; et < 12; ++et) {
            float4 a = *(const float4*)(tok + (size_t)id * 192 + et * 16 + g * 4);
            float4 b = *(const float4*)(pos + (size_t)tt * 192 + et * 16 + g * 4);
            axT[et][0] = a.x + b.x; axT[et][1] = a.y + b.y;
            axT[et][2] = a.z + b.z; axT[et][3] = a.w + b.w;
        }
    }
    __syncthreads();

    const bool hi = (lane & 32) != 0;
    const int xbase = ((lane & 16) << 1) + (lane & 15);
    const char* w2base = (const char*)wch + W2_OFF + lane * 16;

    int q = 0;
#pragma unroll 1
    for (int l = 0; l < L_; ++l) {
        // n2 = LN2(LN1(x)) on D-layout state (params from global/L1)
        lnD(axT, ln1g + l * 192, ln1b + l * 192, g);
        lnD(axT, ln2g + l * 192, ln2b + l * 192, g);
        short8 xf[6];
        packex(axT, lane, xf);
#pragma unroll
        for (int et = 0; et < 12; ++et)
            { axT[et][0] = 0.f; axT[et][1] = 0.f; axT[et][2] = 0.f; axT[et][3] = 0.f; }

#pragma unroll 1
        for (int pp = 0; pp < 12; ++pp) {
            const int P = l * 12 + pp;            // global pair index
            const int cc0 = pp * 2;

            // w2 for chunk0 of this pair: issue first (covered by gemm1 x2 + exch)
            uint4 w2r[12];
            {
                const char* p2 = w2base + (size_t)(2 * P) * CH_BYTES;
#pragma unroll
                for (int e = 0; e < 12; ++e) w2r[e] = *(const uint4*)(p2 + e * 1024);
            }
            // stage next pair's w1 into the other pair-buffer
            if (P + 1 < NP) {
                const char* gnext = (const char*)wch + (size_t)(P + 1) * 2 * CH_BYTES;
                stage3(gnext,            (char*)&wlds[q ^ 1][0],    w, lane);
                stage3(gnext + CH_BYTES, (char*)&wlds[q ^ 1][6144], w, lane);
            }
            // bias1 for both chunks (L1-hot)
            const float* bl = b1g + l * 768 + cc0 * 32;
            float4 b1a0 = *(const float4*)(bl + g * 4);
            float4 b1b0 = *(const float4*)(bl + 16 + g * 4);
            float4 b1a1 = *(const float4*)(bl + 32 + g * 4);
            float4 b1b1 = *(const float4*)(bl + 48 + g * 4);

            const char* wb = (const char*)&wlds[q][0] + lane * 16;

            // gemm1 chunk0 and chunk1: two independent MFMA streams; reads in-loop
            // (compiler schedules ds_read ahead as registers allow — R4-proven)
            f32x4 ah00 = {}, ah01 = {}, ah10 = {}, ah11 = {};
            __builtin_amdgcn_s_setprio(1);
#pragma unroll
            for (int kc = 0; kc < 6; ++kc) {
                uint4 a0 = *(const uint4*)(wb + (kc * 2) * 1024);
                uint4 a1 = *(const uint4*)(wb + (kc * 2 + 1) * 1024);
                ah00 = __builtin_amdgcn_mfma_f32_16x16x32_bf16(__builtin_bit_cast(short8, a0), xf[kc], ah00, 0, 0, 0);
                ah01 = __builtin_amdgcn_mfma_f32_16x16x32_bf16(__builtin_bit_cast(short8, a1), xf[kc], ah01, 0, 0, 0);
            }
#pragma unroll
            for (int kc = 0; kc < 6; ++kc) {
                uint4 a0 = *(const uint4*)(wb + 12288 + (kc * 2) * 1024);
                uint4 a1 = *(const uint4*)(wb + 12288 + (kc * 2 + 1) * 1024);
                ah10 = __builtin_amdgcn_mfma_f32_16x16x32_bf16(__builtin_bit_cast(short8, a0), xf[kc], ah10, 0, 0, 0);
                ah11 = __builtin_amdgcn_mfma_f32_16x16x32_bf16(__builtin_bit_cast(short8, a1), xf[kc], ah11, 0, 0, 0);
            }
            __builtin_amdgcn_s_setprio(0);

            // exchange 0 (bpermutes overlap gemm1_1 tail), gemm2 chunk0
            short8 hb0 = mk_hb(ah00, ah01, b1a0, b1b0, hi, xbase);
            __builtin_amdgcn_s_setprio(1);
#pragma unroll
            for (int et = 0; et < 12; ++et)
                axT[et] = __builtin_amdgcn_mfma_f32_16x16x32_bf16(__builtin_bit_cast(short8, w2r[et]), hb0, axT[et], 0, 0, 0);
            __builtin_amdgcn_s_setprio(0);

            // refill the SAME w2 register set with chunk1's fragments (L1-hot)
            {
                const char* p2 = w2base + (size_t)(2 * P + 1) * CH_BYTES;
#pragma unroll
                for (int e = 0; e < 12; ++e) w2r[e] = *(const uint4*)(p2 + e * 1024);
            }

            // exchange 1, gemm2 chunk1
            short8 hb1 = mk_hb(ah10, ah11, b1a1, b1b1, hi, xbase);
            __builtin_amdgcn_s_setprio(1);
#pragma unroll
            for (int et = 0; et < 12; ++et)
                axT[et] = __builtin_amdgcn_mfma_f32_16x16x32_bf16(__builtin_bit_cast(short8, w2r[et]), hb1, axT[et], 0, 0, 0);
            __builtin_amdgcn_s_setprio(0);

            __syncthreads();     // one barrier per pair: drains glds
            q ^= 1;
        }

        // + bias2 (from global, L1-hot)
#pragma unroll
        for (int et = 0; et < 12; ++et) {
            float4 bb = *(const float4*)(b2g + l * 192 + et * 16 + g * 4);
            axT[et][0] += bb.x; axT[et][1] += bb.y; axT[et][2] += bb.z; axT[et][3] += bb.w;
        }
    }

    // ---- final LN + head ----
    lnD(axT, fng, fnb, g);
    short8 xf[6];
    packex(axT, lane, xf);
    f32x4 av[6] = {};
    __builtin_amdgcn_s_setprio(1);
#pragma unroll
    for (int kc = 0; kc < 6; ++kc)
#pragma unroll
        for (int vt = 0; vt < 6; ++vt) {
            short8 wf = *(const short8*)(wfr + (size_t)(kc * 6 + vt) * 512 + lane * 8);
            av[vt] = __builtin_amdgcn_mfma_f32_16x16x32_bf16(wf, xf[kc], av[vt], 0, 0, 0);
        }
    __builtin_amdgcn_s_setprio(0);

    float vv[6][4];
#pragma unroll
    for (int vt = 0; vt < 6; ++vt) {
        float4 bb = *(const float4*)(bfb + vt * 16 + g * 4);
        vv[vt][0] = av[vt][0] + bb.x;
        vv[vt][1] = av[vt][1] + bb.y;
        vv[vt][2] = av[vt][2] + bb.z;
        vv[vt][3] = av[vt][3] + bb.w;
    }
    float mx = -1e30f;
#pragma unroll
    for (int vt = 0; vt < 6; ++vt)
#pragma unroll
        for (int r = 0; r < 4; ++r) mx = fmaxf(mx, vv[vt][r]);
    mx = fmaxf(mx, __shfl_xor(mx, 16));
    mx = fmaxf(mx, __shfl_xor(mx, 32));
    float se = 0.f;
#pragma unroll
    for (int vt = 0; vt < 6; ++vt)
#pragma unroll
        for (int r = 0; r < 4; ++r) se += expf(vv[vt][r] - mx);
    se += __shfl_xor(se, 16);
    se += __shfl_xor(se, 32);
    float lse = logf(se) + mx;
    int tgt = tgp[myrow];
    float lsum = 0.f;
#pragma unroll
    for (int vt = 0; vt < 6; ++vt)
#pragma unroll
        for (int r = 0; r < 4; ++r)
            if (tgt == vt * 16 + g * 4 + r) lsum += lse - vv[vt][r];
#pragma unroll
    for (int vt = 0; vt < 6; ++vt) {
        float4 o;
        o.x = vv[vt][0]; o.y = vv[vt][1]; o.z = vv[vt][2]; o.w = vv[vt][3];
        *(float4*)(pred + (size_t)myrow * 96 + vt * 16 + g * 4) = o;
    }
#pragma unroll
    for (int m = 1; m < 64; m <<= 1) lsum += __shfl_xor(lsum, m);
    if (lane == 0) lsred[w] = lsum;
    __syncthreads();
    if (tid == 0) partial[blockIdx.x] = lsred[0] + lsred[1] + lsred[2] + lsred[3];
}

__global__ void lossred_k(const float* __restrict__ partial, float* __restrict__ out)
{
    __shared__ double sd[256];
    int t = threadIdx.x;
    sd[t] = (double)partial[t] + (double)partial[t + 256];
    __syncthreads();
    for (int s = 128; s > 0; s >>= 1) {
        if (t < s) sd[t] += sd[t + s];
        __syncthreads();
    }
    if (t == 0) out[0] = (float)(sd[0] / (double)R_);
}

extern "C" void kernel_launch(void* const* d_in, const int* in_sizes, int n_in,
                              void* d_out, int out_size, void* d_ws, size_t ws_size,
                              hipStream_t stream)
{
    (void)in_sizes; (void)n_in; (void)out_size; (void)ws_size;
    const int*   index   = (const int*)  d_in[0];
    const int*   targets = (const int*)  d_in[1];
    const float* tok     = (const float*)d_in[2];
    const float* pos     = (const float*)d_in[3];
    const float* ln1g    = (const float*)d_in[4];
    const float* ln1b    = (const float*)d_in[5];
    const float* ln2g    = (const float*)d_in[6];
    const float* ln2b    = (const float*)d_in[7];
    // d_in[8..10] = Wq/Wk/Wv: dead in the reference forward
    const float* W1      = (const float*)d_in[11];
    const float* b1      = (const float*)d_in[12];
    const float* W2      = (const float*)d_in[13];
    const float* b2      = (const float*)d_in[14];
    const float* fng     = (const float*)d_in[15];
    const float* fnb     = (const float*)d_in[16];
    const float* Wf      = (const float*)d_in[17];
    const float* bfv     = (const float*)d_in[18];

    ushort_t* wch = (ushort_t*)d_ws;                        // [144][12288] us (24576B chunks)
    ushort_t* wfr = wch + (size_t)NT * CH_US;               // [36][512] head fragments
    float* partial = (float*)(wfr + 36 * 512);              // [512]
    float* pred  = (float*)d_out;
    float* lossp = pred + (size_t)R_ * V_;

    const int nconv = 2 * 884736 + 36 * 512;                // 1787904 = 6984*256
    wconv_k<<<nconv / 256, 256, 0, stream>>>(W1, W2, Wf, wch, wfr);
    net_k<<<512, 256, 0, stream>>>(index, targets, tok, pos, ln1g, ln1b, ln2g, ln2b,
                                   b1, b2, fng, fnb, bfv, wch, wfr, pred, partial);
    lossred_k<<<1, 256, 0, stream>>>(partial, lossp);
}

// Round 9
// 149.864 us; speedup vs baseline: 2.7177x; 1.4963x over previous
//
#include <hip/hip_runtime.h>

typedef __attribute__((ext_vector_type(4))) float f32x4;
typedef __attribute__((ext_vector_type(8))) short short8;
typedef unsigned short ushort_t;
typedef unsigned int uint_t;

#define R_  32768
#define L_  6
#define EPS_ 1e-5f

// fragment-ordered weights in workspace:
//  w1s [L][2 half][4 wave][6 ft][6 kc][512]   (A-frags 16f x 32k)
//  w2s [L][2 half][4 wave][3 ei][12 kc2][512] (A-frags 16e x 32f)
//  wfr [6 vt][6 kc][512]                      (A-frags 16v x 32k)
#define NW_ 884736

__device__ __forceinline__ ushort_t f2bf(float f) {
    uint_t i = __builtin_bit_cast(uint_t, f);
    uint_t r = (i + 0x7fffu + ((i >> 16) & 1u)) >> 16;   // RNE
    return (ushort_t)r;
}
__device__ __forceinline__ uint_t cvtpk(float a, float b) {
    uint_t r;
    asm("v_cvt_pk_bf16_f32 %0, %1, %2" : "=v"(r) : "v"(a), "v"(b));
    return r;
}

// ---------------- weight convert: per-wave-slice fragment-ordered ----------------
__global__ void wconv_k(const float* __restrict__ W1, const float* __restrict__ W2,
                        const float* __restrict__ Wf,
                        ushort_t* __restrict__ w1s, ushort_t* __restrict__ w2s,
                        ushort_t* __restrict__ wfr)
{
    int i = blockIdx.x * 256 + threadIdx.x;
    if (i < NW_) {    // w1 frags: global frag q = (((l*2+half)*4+wv)*6+ft)*6+kc
        int j = i & 7, li = (i >> 3) & 63, q = i >> 9;
        int kc = q % 6; q /= 6;
        int ft = q % 6; q /= 6;
        int wv = q & 3; q >>= 2;
        int half = q & 1; int l = q >> 1;
        int f = half * 384 + wv * 96 + ft * 16 + (li & 15);
        int k = kc * 32 + ((li >> 4) << 3) + j;
        w1s[i] = f2bf(W1[((size_t)l * 192 + k) * 768 + f]);
        return;
    }
    i -= NW_;
    if (i < NW_) {    // w2 frags: q = (((l*2+half)*4+wv)*3+ei)*12+kc2
        int j = i & 7, li = (i >> 3) & 63, q = i >> 9;
        int kc2 = q % 12; q /= 12;
        int ei = q % 3; q /= 3;
        int wv = q & 3; q >>= 2;
        int half = q & 1; int l = q >> 1;
        int e = (wv + 4 * ei) * 16 + (li & 15);
        int k = half * 384 + kc2 * 32 + ((li >> 4) << 3) + j;
        w2s[i] = f2bf(W2[((size_t)l * 768 + k) * 192 + e]);
        return;
    }
    i -= NW_;
    if (i < 36 * 512) {   // head frags: q = vt*6+kc
        int j = i & 7, li = (i >> 3) & 63, q = i >> 9;
        int kc = q % 6, vt = q / 6;
        int v = vt * 16 + (li & 15);
        int k = kc * 32 + ((li >> 4) << 3) + j;
        wfr[i] = f2bf(Wf[(size_t)k * 96 + v]);
    }
}

// ---------------- whole network: block-cooperative, 64 rows/block ----------------
__global__ __launch_bounds__(256, 2) void net_k(
    const int* __restrict__ idxp, const int* __restrict__ tgp,
    const float* __restrict__ tok, const float* __restrict__ pos,
    const float* __restrict__ ln1g, const float* __restrict__ ln1b,
    const float* __restrict__ ln2g, const float* __restrict__ ln2b,
    const float* __restrict__ b1g, const float* __restrict__ b2g,
    const float* __restrict__ fng, const float* __restrict__ fnb,
    const float* __restrict__ bfb,
    const ushort_t* __restrict__ w1s, const ushort_t* __restrict__ w2s,
    const ushort_t* __restrict__ wfr,
    float* __restrict__ pred, float* __restrict__ partial)
{
    __shared__ __align__(16) ushort_t xb[6 * 4 * 512];     // x B-frags  [kc][rg][512] 24KB
    __shared__ __align__(16) ushort_t hbl[12 * 4 * 512];   // h B-frags  [kc2][rg][512] 48KB
    __shared__ __align__(16) float lnS1[64][4], lnQ1[64][4];
    __shared__ __align__(16) float lnS2[64][4], lnQ2[64][4];
    __shared__ float lsred[4];

    const int tid = threadIdx.x, lane = tid & 63, w = tid >> 6;
    const int c = lane & 15, g = lane >> 4;
    const int row0 = blockIdx.x * 64;

    // x state distributed: wave w owns e-tiles {w, w+4, w+8}; D-layout
    // xac[i][rg]: lane(g,c) holds x[e=(w+4i)*16+g*4+r][row = rg*16+c]
    f32x4 xac[3][4];

    // ---- embedding ----
#pragma unroll
    for (int rg = 0; rg < 4; ++rg) {
        int row = row0 + rg * 16 + c;
        int id = idxp[row];
        int tt = row & 127;
#pragma unroll
        for (int i = 0; i < 3; ++i) {
            int e0 = (w + 4 * i) * 16 + g * 4;
            float4 a = *(const float4*)(tok + (size_t)id * 192 + e0);
            float4 b = *(const float4*)(pos + (size_t)tt * 192 + e0);
            xac[i][rg][0] = a.x + b.x; xac[i][rg][1] = a.y + b.y;
            xac[i][rg][2] = a.z + b.z; xac[i][rg][3] = a.w + b.w;
        }
    }

#pragma unroll 1
    for (int l = 0; l < L_; ++l) {
        // ---- LN1 stats (cross-wave via LDS) ----
#pragma unroll
        for (int rg = 0; rg < 4; ++rg) {
            float s = 0.f, sq = 0.f;
#pragma unroll
            for (int i = 0; i < 3; ++i)
#pragma unroll
                for (int r = 0; r < 4; ++r) { float v = xac[i][rg][r]; s += v; sq += v * v; }
            s += __shfl_xor(s, 16); sq += __shfl_xor(sq, 16);
            s += __shfl_xor(s, 32); sq += __shfl_xor(sq, 32);
            if (g == 0) { lnS1[rg * 16 + c][w] = s; lnQ1[rg * 16 + c][w] = sq; }
        }
        __syncthreads();
        // ---- apply LN1, compute LN2 stats ----
#pragma unroll
        for (int rg = 0; rg < 4; ++rg) {
            float4 S = *(const float4*)lnS1[rg * 16 + c];
            float4 Q = *(const float4*)lnQ1[rg * 16 + c];
            float mu = (S.x + S.y + S.z + S.w) * (1.f / 192.f);
            float var = (Q.x + Q.y + Q.z + Q.w) * (1.f / 192.f) - mu * mu;
            float ri = rsqrtf(var + EPS_);
            float s2 = 0.f, q2 = 0.f;
#pragma unroll
            for (int i = 0; i < 3; ++i) {
                int e0 = (w + 4 * i) * 16 + g * 4;
                float4 gg = *(const float4*)(ln1g + l * 192 + e0);
                float4 bb = *(const float4*)(ln1b + l * 192 + e0);
                float n0 = (xac[i][rg][0] - mu) * ri * gg.x + bb.x;
                float n1 = (xac[i][rg][1] - mu) * ri * gg.y + bb.y;
                float n2 = (xac[i][rg][2] - mu) * ri * gg.z + bb.z;
                float n3 = (xac[i][rg][3] - mu) * ri * gg.w + bb.w;
                xac[i][rg][0] = n0; xac[i][rg][1] = n1; xac[i][rg][2] = n2; xac[i][rg][3] = n3;
                s2 += n0 + n1 + n2 + n3;
                q2 += n0 * n0 + n1 * n1 + n2 * n2 + n3 * n3;
            }
            s2 += __shfl_xor(s2, 16); q2 += __shfl_xor(q2, 16);
            s2 += __shfl_xor(s2, 32); q2 += __shfl_xor(q2, 32);
            if (g == 0) { lnS2[rg * 16 + c][w] = s2; lnQ2[rg * 16 + c][w] = q2; }
        }
        __syncthreads();
        // ---- apply LN2, pack n2 -> xb B-frags, zero accumulator ----
#pragma unroll
        for (int rg = 0; rg < 4; ++rg) {
            float4 S = *(const float4*)lnS2[rg * 16 + c];
            float4 Q = *(const float4*)lnQ2[rg * 16 + c];
            float mu = (S.x + S.y + S.z + S.w) * (1.f / 192.f);
            float var = (Q.x + Q.y + Q.z + Q.w) * (1.f / 192.f) - mu * mu;
            float ri = rsqrtf(var + EPS_);
#pragma unroll
            for (int i = 0; i < 3; ++i) {
                int et = w + 4 * i;
                int e0 = et * 16 + g * 4;
                float4 gg = *(const float4*)(ln2g + l * 192 + e0);
                float4 bb = *(const float4*)(ln2b + l * 192 + e0);
                float y0 = (xac[i][rg][0] - mu) * ri * gg.x + bb.x;
                float y1 = (xac[i][rg][1] - mu) * ri * gg.y + bb.y;
                float y2 = (xac[i][rg][2] - mu) * ri * gg.z + bb.z;
                float y3 = (xac[i][rg][3] - mu) * ri * gg.w + bb.w;
                uint_t d0 = cvtpk(y0, y1), d1 = cvtpk(y2, y3);
                int kc = et >> 1, floc = ((et & 1) << 4) + g * 4;
                int us = (kc * 4 + rg) * 512 + ((floc >> 3) * 16 + c) * 8 + (floc & 7);
                *(uint2*)(xb + us) = make_uint2(d0, d1);
                xac[i][rg][0] = 0.f; xac[i][rg][1] = 0.f; xac[i][rg][2] = 0.f; xac[i][rg][3] = 0.f;
            }
        }
        __syncthreads();

        // ---- FFN: two f-halves of 384 ----
#pragma unroll 1
        for (int half = 0; half < 2; ++half) {
            // gemm1: wave's 96-f slice, weights global->reg, x from LDS
            const ushort_t* w1p = w1s + ((size_t)((l * 2 + half) * 4 + w) * 36) * 512 + lane * 8;
#pragma unroll
            for (int fth = 0; fth < 2; ++fth) {
                short8 wa[18];
#pragma unroll
                for (int q = 0; q < 18; ++q) wa[q] = *(const short8*)(w1p + (fth * 18 + q) * 512);
                float4 bbv[3];
#pragma unroll
                for (int f3 = 0; f3 < 3; ++f3)
                    bbv[f3] = *(const float4*)(b1g + l * 768 + half * 384 + w * 96 + (fth * 3 + f3) * 16 + g * 4);
#pragma unroll
                for (int rg = 0; rg < 4; ++rg) {
                    short8 xbf[6];
#pragma unroll
                    for (int kc = 0; kc < 6; ++kc)
                        xbf[kc] = *(const short8*)(xb + (kc * 4 + rg) * 512 + lane * 8);
#pragma unroll
                    for (int f3 = 0; f3 < 3; ++f3) {
                        f32x4 acc = {};
                        __builtin_amdgcn_s_setprio(1);
#pragma unroll
                        for (int kc = 0; kc < 6; ++kc)
                            acc = __builtin_amdgcn_mfma_f32_16x16x32_bf16(wa[f3 * 6 + kc], xbf[kc], acc, 0, 0, 0);
                        __builtin_amdgcn_s_setprio(0);
                        float y0 = fmaxf(acc[0] + bbv[f3].x, 0.f);
                        float y1 = fmaxf(acc[1] + bbv[f3].y, 0.f);
                        float y2 = fmaxf(acc[2] + bbv[f3].z, 0.f);
                        float y3 = fmaxf(acc[3] + bbv[f3].w, 0.f);
                        uint_t d0 = cvtpk(y0, y1), d1 = cvtpk(y2, y3);
                        int ft = fth * 3 + f3;
                        int kc2 = w * 3 + (ft >> 1);
                        int floc = ((ft & 1) << 4) + g * 4;
                        int us = (kc2 * 4 + rg) * 512 + ((floc >> 3) * 16 + c) * 8 + (floc & 7);
                        *(uint2*)(hbl + us) = make_uint2(d0, d1);
                    }
                }
            }
            __syncthreads();

            // gemm2: wave's 48-e slice, weights global->reg, h from LDS
            const ushort_t* w2p = w2s + ((size_t)((l * 2 + half) * 4 + w) * 36) * 512 + lane * 8;
#pragma unroll
            for (int kh = 0; kh < 2; ++kh) {
                short8 wr[18];
#pragma unroll
                for (int ei = 0; ei < 3; ++ei)
#pragma unroll
                    for (int k6 = 0; k6 < 6; ++k6)
                        wr[ei * 6 + k6] = *(const short8*)(w2p + (ei * 12 + kh * 6 + k6) * 512);
#pragma unroll
                for (int rg = 0; rg < 4; ++rg) {
                    short8 hbf[6];
#pragma unroll
                    for (int k6 = 0; k6 < 6; ++k6)
                        hbf[k6] = *(const short8*)(hbl + ((kh * 6 + k6) * 4 + rg) * 512 + lane * 8);
                    __builtin_amdgcn_s_setprio(1);
#pragma unroll
                    for (int ei = 0; ei < 3; ++ei)
#pragma unroll
                        for (int k6 = 0; k6 < 6; ++k6)
                            xac[ei][rg] = __builtin_amdgcn_mfma_f32_16x16x32_bf16(wr[ei * 6 + k6], hbf[k6], xac[ei][rg], 0, 0, 0);
                    __builtin_amdgcn_s_setprio(0);
                }
            }
            __syncthreads();
        }

        // ---- + bias2 ----
#pragma unroll
        for (int i = 0; i < 3; ++i) {
            int e0 = (w + 4 * i) * 16 + g * 4;
            float4 bb = *(const float4*)(b2g + l * 192 + e0);
#pragma unroll
            for (int rg = 0; rg < 4; ++rg) {
                xac[i][rg][0] += bb.x; xac[i][rg][1] += bb.y;
                xac[i][rg][2] += bb.z; xac[i][rg][3] += bb.w;
            }
        }
    }

    // ---- final LN ----
#pragma unroll
    for (int rg = 0; rg < 4; ++rg) {
        float s = 0.f, sq = 0.f;
#pragma unroll
        for (int i = 0; i < 3; ++i)
#pragma unroll
            for (int r = 0; r < 4; ++r) { float v = xac[i][rg][r]; s += v; sq += v * v; }
        s += __shfl_xor(s, 16); sq += __shfl_xor(sq, 16);
        s += __shfl_xor(s, 32); sq += __shfl_xor(sq, 32);
        if (g == 0) { lnS1[rg * 16 + c][w] = s; lnQ1[rg * 16 + c][w] = sq; }
    }
    __syncthreads();
#pragma unroll
    for (int rg = 0; rg < 4; ++rg) {
        float4 S = *(const float4*)lnS1[rg * 16 + c];
        float4 Q = *(const float4*)lnQ1[rg * 16 + c];
        float mu = (S.x + S.y + S.z + S.w) * (1.f / 192.f);
        float var = (Q.x + Q.y + Q.z + Q.w) * (1.f / 192.f) - mu * mu;
        float ri = rsqrtf(var + EPS_);
#pragma unroll
        for (int i = 0; i < 3; ++i) {
            int et = w + 4 * i;
            int e0 = et * 16 + g * 4;
            float4 gg = *(const float4*)(fng + e0);
            float4 bb = *(const float4*)(fnb + e0);
            float y0 = (xac[i][rg][0] - mu) * ri * gg.x + bb.x;
            float y1 = (xac[i][rg][1] - mu) * ri * gg.y + bb.y;
            float y2 = (xac[i][rg][2] - mu) * ri * gg.z + bb.z;
            float y3 = (xac[i][rg][3] - mu) * ri * gg.w + bb.w;
            uint_t d0 = cvtpk(y0, y1), d1 = cvtpk(y2, y3);
            int kc = et >> 1, floc = ((et & 1) << 4) + g * 4;
            int us = (kc * 4 + rg) * 512 + ((floc >> 3) * 16 + c) * 8 + (floc & 7);
            *(uint2*)(xb + us) = make_uint2(d0, d1);
        }
    }
    __syncthreads();

    // ---- head: wave w handles rows rg=w (16 rows), all 96 vocab ----
    short8 wfh[36];
    {
        const ushort_t* wfp = wfr + lane * 8;
#pragma unroll
        for (int q = 0; q < 36; ++q) wfh[q] = *(const short8*)(wfp + q * 512);
    }
    short8 xbf[6];
#pragma unroll
    for (int kc = 0; kc < 6; ++kc)
        xbf[kc] = *(const short8*)(xb + (kc * 4 + w) * 512 + lane * 8);
    f32x4 av[6] = {};
    __builtin_amdgcn_s_setprio(1);
#pragma unroll
    for (int vt = 0; vt < 6; ++vt)
#pragma unroll
        for (int kc = 0; kc < 6; ++kc)
            av[vt] = __builtin_amdgcn_mfma_f32_16x16x32_bf16(wfh[vt * 6 + kc], xbf[kc], av[vt], 0, 0, 0);
    __builtin_amdgcn_s_setprio(0);

    float vv[6][4];
#pragma unroll
    for (int vt = 0; vt < 6; ++vt) {
        float4 bb = *(const float4*)(bfb + vt * 16 + g * 4);
        vv[vt][0] = av[vt][0] + bb.x;
        vv[vt][1] = av[vt][1] + bb.y;
        vv[vt][2] = av[vt][2] + bb.z;
        vv[vt][3] = av[vt][3] + bb.w;
    }
    float mx = -1e30f;
#pragma unroll
    for (int vt = 0; vt < 6; ++vt)
#pragma unroll
        for (int r = 0; r < 4; ++r) mx = fmaxf(mx, vv[vt][r]);
    mx = fmaxf(mx, __shfl_xor(mx, 16));
    mx = fmaxf(mx, __shfl_xor(mx, 32));
    float se = 0.f;
#pragma unroll
    for (int vt = 0; vt < 6; ++vt)
#pragma unroll
        for (int r = 0; r < 4; ++r) se += expf(vv[vt][r] - mx);
    se += __shfl_xor(se, 16);
    se += __shfl_xor(se, 32);
    float lse = logf(se) + mx;
    int myrow = row0 + w * 16 + c;
    int tgt = tgp[myrow];
    float lsum = 0.f;
#pragma unroll
    for (int vt = 0; vt < 6; ++vt)
#pragma unroll
        for (int r = 0; r < 4; ++r)
            if (tgt == vt * 16 + g * 4 + r) lsum += lse - vv[vt][r];
#pragma unroll
    for (int vt = 0; vt < 6; ++vt) {
        float4 o;
        o.x = vv[vt][0]; o.y = vv[vt][1]; o.z = vv[vt][2]; o.w = vv[vt][3];
        *(float4*)(pred + (size_t)myrow * 96 + vt * 16 + g * 4) = o;
    }
#pragma unroll
    for (int m = 1; m < 64; m <<= 1) lsum += __shfl_xor(lsum, m);
    if (lane == 0) lsred[w] = lsum;
    __syncthreads();
    if (tid == 0) partial[blockIdx.x] = lsred[0] + lsred[1] + lsred[2] + lsred[3];
}

__global__ void lossred_k(const float* __restrict__ partial, float* __restrict__ out)
{
    __shared__ double sd[256];
    int t = threadIdx.x;
    sd[t] = (double)partial[t] + (double)partial[t + 256];
    __syncthreads();
    for (int s = 128; s > 0; s >>= 1) {
        if (t < s) sd[t] += sd[t + s];
        __syncthreads();
    }
    if (t == 0) out[0] = (float)(sd[0] / (double)R_);
}

extern "C" void kernel_launch(void* const* d_in, const int* in_sizes, int n_in,
                              void* d_out, int out_size, void* d_ws, size_t ws_size,
                              hipStream_t stream)
{
    (void)in_sizes; (void)n_in; (void)out_size; (void)ws_size;
    const int*   index   = (const int*)  d_in[0];
    const int*   targets = (const int*)  d_in[1];
    const float* tok     = (const float*)d_in[2];
    const float* pos     = (const float*)d_in[3];
    const float* ln1g    = (const float*)d_in[4];
    const float* ln1b    = (const float*)d_in[5];
    const float* ln2g    = (const float*)d_in[6];
    const float* ln2b    = (const float*)d_in[7];
    // d_in[8..10] = Wq/Wk/Wv: dead in the reference forward
    const float* W1      = (const float*)d_in[11];
    const float* b1      = (const float*)d_in[12];
    const float* W2      = (const float*)d_in[13];
    const float* b2      = (const float*)d_in[14];
    const float* fng     = (const float*)d_in[15];
    const float* fnb     = (const float*)d_in[16];
    const float* Wf      = (const float*)d_in[17];
    const float* bfv     = (const float*)d_in[18];

    ushort_t* w1s = (ushort_t*)d_ws;                        // [884736]
    ushort_t* w2s = w1s + NW_;                              // [884736]
    ushort_t* wfr = w2s + NW_;                              // [18432]
    float* partial = (float*)(wfr + 36 * 512);              // [512]
    float* pred  = (float*)d_out;
    float* lossp = pred + (size_t)R_ * 96;

    const int nconv = 2 * NW_ + 36 * 512;                   // 1787904 = 6984*256
    wconv_k<<<nconv / 256, 256, 0, stream>>>(W1, W2, Wf, w1s, w2s, wfr);
    net_k<<<512, 256, 0, stream>>>(index, targets, tok, pos, ln1g, ln1b, ln2g, ln2b,
                                   b1, b2, fng, fnb, bfv, w1s, w2s, wfr, pred, partial);
    lossred_k<<<1, 256, 0, stream>>>(partial, lossp);
}